// Round 1
// baseline (928.870 us; speedup 1.0000x reference)
//
#include <hip/hip_runtime.h>
#include <cstdint>
#include <cstddef>

#define EMBED 4096
#define NEXP  64
#define CAP   256
#define SEQ   8192
#define NBATCH 4
#define ROWS  32768            // NBATCH * SEQ
#define BM    128              // rows per block
#define BK    64               // k-chunk per LDS tile
#define NTHREADS 512

// ---------------------------------------------------------------------------
// Kernel A: f32 GEMM (logits = x @ W^T) + fused softmax epilogue.
// Writes logits, probs, and zeros the mask region.
// LDS layout (transposed: [k][row]) so compute reads are ds_read_b128 with
// 4 distinct addresses (16-way broadcast) for x and 2-way (free) for W.
// Double-buffered BK=64 tiles: 2*(128*64 + 64*64)*4B = 96 KiB LDS.
// ---------------------------------------------------------------------------
__global__ __launch_bounds__(NTHREADS) void gemm_softmax(
    const float* __restrict__ x, const float* __restrict__ W,
    float* __restrict__ out)
{
    __shared__ float lds[24576];   // xs[2] @ 0,8192 ; ws[2] @ 16384,20480

    const int tid  = threadIdx.x;
    const int row0 = blockIdx.x * BM;

    // staging mapping: q = k-quad (16 quads of 4 k), rg = 4-row group (32)
    const int q  = tid & 15;
    const int rg = tid >> 4;           // 0..31
    // compute mapping: tc = expert quad (16), tr = row quad (32)
    const int tc = tid & 15;
    const int tr = tid >> 4;           // 0..31

    float acc[4][4];
#pragma unroll
    for (int i = 0; i < 4; ++i)
#pragma unroll
        for (int j = 0; j < 4; ++j) acc[i][j] = 0.f;

    const float* xp[4];
#pragma unroll
    for (int j = 0; j < 4; ++j)
        xp[j] = x + (size_t)(row0 + 4 * rg + j) * EMBED + 4 * q;
    const float* wp[4];
#pragma unroll
    for (int j = 0; j < 4; ++j)
        wp[j] = W + (size_t)(4 * rg + j) * EMBED + 4 * q;  // used only if rg<16

    float4 xr[4];
    float4 wr[4];

    auto issue = [&](int kb) {
#pragma unroll
        for (int j = 0; j < 4; ++j)
            xr[j] = *(const float4*)(xp[j] + kb);
        if (rg < 16) {
#pragma unroll
            for (int j = 0; j < 4; ++j)
                wr[j] = *(const float4*)(wp[j] + kb);
        }
    };

    auto commit = [&](int buf) {
        // 4x4 register transpose, then vectorized LDS writes to [k][row]
        float* xd = lds + buf * 8192;
        const float* f = (const float*)&xr[0];
#pragma unroll
        for (int c = 0; c < 4; ++c) {
            float4 t = make_float4(f[c], f[4 + c], f[8 + c], f[12 + c]);
            *(float4*)(xd + (4 * q + c) * BM + 4 * rg) = t;
        }
        if (rg < 16) {
            float* wd = lds + 16384 + buf * 4096;
            const float* g = (const float*)&wr[0];
#pragma unroll
            for (int c = 0; c < 4; ++c) {
                float4 t = make_float4(g[c], g[4 + c], g[8 + c], g[12 + c]);
                *(float4*)(wd + (4 * q + c) * NEXP + 4 * rg) = t;
            }
        }
    };

    auto compute = [&](int buf) {
        const float* xsrc = lds + buf * 8192 + 4 * tr;
        const float* wsrc = lds + 16384 + buf * 4096 + 4 * tc;
#pragma unroll 8
        for (int k = 0; k < BK; ++k) {
            float a[4], b[4];
            *(float4*)a = *(const float4*)(xsrc + k * BM);
            *(float4*)b = *(const float4*)(wsrc + k * NEXP);
#pragma unroll
            for (int i = 0; i < 4; ++i)
#pragma unroll
                for (int j = 0; j < 4; ++j)
                    acc[i][j] = fmaf(a[i], b[j], acc[i][j]);
        }
    };

    issue(0);
    commit(0);
    __syncthreads();

    const int NTILE = EMBED / BK;  // 64
    for (int t = 0; t < NTILE; ++t) {
        const int cur = t & 1;
        if (t + 1 < NTILE) issue((t + 1) * BK);
        compute(cur);
        if (t + 1 < NTILE) commit(cur ^ 1);
        __syncthreads();
    }

    // ---- fused softmax epilogue ----
    // Row r's 64 experts live in the 16 lanes sharing tr (lane low-4 bits = tc)
    float* mask_o  = out;
    float* probs_o = out + (size_t)ROWS * NEXP;
    float* log_o   = out + (size_t)2 * ROWS * NEXP;

#pragma unroll
    for (int i = 0; i < 4; ++i) {
        float m = fmaxf(fmaxf(acc[i][0], acc[i][1]), fmaxf(acc[i][2], acc[i][3]));
#pragma unroll
        for (int off = 1; off < 16; off <<= 1)
            m = fmaxf(m, __shfl_xor(m, off, 64));
        float e0 = expf(acc[i][0] - m);
        float e1 = expf(acc[i][1] - m);
        float e2 = expf(acc[i][2] - m);
        float e3 = expf(acc[i][3] - m);
        float s = e0 + e1 + e2 + e3;
#pragma unroll
        for (int off = 1; off < 16; off <<= 1)
            s += __shfl_xor(s, off, 64);
        float rs = 1.0f / s;
        size_t rowoff = (size_t)(row0 + 4 * tr + i) * NEXP + 4 * tc;
        *(float4*)(probs_o + rowoff) = make_float4(e0 * rs, e1 * rs, e2 * rs, e3 * rs);
        *(float4*)(log_o + rowoff)   = make_float4(acc[i][0], acc[i][1], acc[i][2], acc[i][3]);
        *(float4*)(mask_o + rowoff)  = make_float4(0.f, 0.f, 0.f, 0.f);
    }
}

// ---------------------------------------------------------------------------
// Kernel B: per (b,e) column, exact top-256-of-8192 selection on probs via
// 4-pass radix select on f32 bit patterns (all probs > 0 -> monotone uint).
// Sets mask[b, s, 0] = 1 for selected tokens (union across experts is
// naturally handled: concurrent writers all store 1.0f).
// ---------------------------------------------------------------------------
__global__ __launch_bounds__(256) void topk_mask(
    const float* __restrict__ probs, float* __restrict__ mask)
{
    __shared__ unsigned int hist[256];
    __shared__ unsigned int sh_prefix, sh_kth, sh_eq;

    const int tid = threadIdx.x;
    const int b = blockIdx.x >> 6;
    const int e = blockIdx.x & 63;

    const float* p = probs + (size_t)b * SEQ * NEXP + e;

    unsigned int bits[32];
#pragma unroll
    for (int i = 0; i < 32; ++i) {
        const int s = (i << 8) + tid;
        bits[i] = __float_as_uint(p[(size_t)s * NEXP]);
    }

    unsigned int prefix = 0, kth = CAP;

    for (int pass = 0; pass < 4; ++pass) {
        const int shift = 24 - 8 * pass;
        hist[tid] = 0;
        __syncthreads();

        const unsigned int himask =
            (pass == 0) ? 0u : (0xFFFFFFFFu << (shift + 8));
#pragma unroll
        for (int i = 0; i < 32; ++i) {
            if ((bits[i] & himask) == prefix)
                atomicAdd(&hist[(bits[i] >> shift) & 0xFF], 1u);
        }
        __syncthreads();

        // inclusive suffix scan: hist[t] = # candidates with byte >= t
        unsigned int v = hist[tid];
        for (int off = 1; off < 256; off <<= 1) {
            unsigned int add = (tid + off < 256) ? hist[tid + off] : 0u;
            __syncthreads();
            v += add;
            hist[tid] = v;
            __syncthreads();
        }

        const unsigned int snext = (tid == 255) ? 0u : hist[tid + 1];
        if (v >= kth && snext < kth) {      // unique crossing
            sh_prefix = prefix | ((unsigned int)tid << shift);
            sh_kth    = kth - snext;        // rank within this bin
        }
        __syncthreads();
        prefix = sh_prefix;
        kth    = sh_kth;
        __syncthreads();
    }

    if (tid == 0) sh_eq = 0;
    __syncthreads();

    const unsigned int T = prefix;          // bit pattern of 256th largest
    float* mcol = mask + (size_t)b * SEQ * NEXP;   // channel 0 of batch b
#pragma unroll
    for (int i = 0; i < 32; ++i) {
        const int s = (i << 8) + tid;
        bool sel = bits[i] > T;
        if (!sel && bits[i] == T) {
            unsigned int pos = atomicAdd(&sh_eq, 1u);
            sel = (pos < kth);              // fill remaining slots among ties
        }
        if (sel) mcol[(size_t)s * NEXP] = 1.0f;
    }
}

// ---------------------------------------------------------------------------
extern "C" void kernel_launch(void* const* d_in, const int* in_sizes, int n_in,
                              void* d_out, int out_size, void* d_ws, size_t ws_size,
                              hipStream_t stream)
{
    const float* x = (const float*)d_in[0];
    const float* W = (const float*)d_in[1];
    float* out = (float*)d_out;

    dim3 gA(ROWS / BM), bA(NTHREADS);
    hipLaunchKernelGGL(gemm_softmax, gA, bA, 0, stream, x, W, out);

    const float* probs = out + (size_t)ROWS * NEXP;
    dim3 gB(NBATCH * NEXP), bB(256);
    hipLaunchKernelGGL(topk_mask, gB, bB, 0, stream, probs, out);
}